// Round 8
// baseline (46.854 us; speedup 1.0000x reference)
//
#include <hip/hip_runtime.h>

// LMHT neuron with multi-level positive/negative quantization.
// x: [T=8, B=64, N=65536] fp32; v_threshold: [1] fp32.
// Per neuron (flattened B*N): v += x[t]; k = trunc(clamp(v/th, -4, 4));
// out[t] = k*th; v -= out[t].
// Memory-bound. History: R4 47.2us baseline; R6 nt-store neutral; R7
// sc0sc1nt 44.6us but VGPR=28 -> loads NOT hoisted (asm "memory" clobber
// serialized the t-loop). This round: explicit 8-wide load phase (8
// independent global_load_dwordx4 in flight per wave) then compute+store.
// Structural traffic: 131 MB read + 131 MB write = 262 MB demand
// -> 41.7 us at the 6.29 TB/s copy ceiling.

constexpr int   kT = 8;
constexpr float kL = 4.0f;

typedef float f32x4 __attribute__((ext_vector_type(4)));

__device__ __forceinline__ float quant_pn(float v, float th) {
    float k = v / th;                       // true IEEE div; matches jnp semantics
    k = fminf(fmaxf(k, -kL), kL);           // clamp to [-L, L]
    k = truncf(k);                          // floor-toward-zero == where(k>0,floor)+where(k<0,ceil)
    return k * th;
}

__device__ __forceinline__ f32x4 step4(f32x4& v, f32x4 xt, float th) {
    f32x4 o;
    v.x += xt.x;  o.x = quant_pn(v.x, th);  v.x -= o.x;
    v.y += xt.y;  o.y = quant_pn(v.y, th);  v.y -= o.y;
    v.z += xt.z;  o.z = quant_pn(v.z, th);  v.z -= o.z;
    v.w += xt.w;  o.w = quant_pn(v.w, th);  v.w -= o.w;
    return o;
}

__global__ __launch_bounds__(256) void lmht_pn_kernel(
    const f32x4* __restrict__ x,
    const float* __restrict__ vth,
    f32x4* __restrict__ out,
    int n4)   // (B*N)/4 float4 elements per timestep
{
    const float th = vth[0];
    const size_t i = (size_t)blockIdx.x * blockDim.x + threadIdx.x;
    const size_t s = (size_t)n4;

    // Phase 1: issue all 8 loads back-to-back -> 8 outstanding
    // global_load_dwordx4 per wave (max memory-level parallelism).
    const f32x4 x0 = x[0 * s + i];
    const f32x4 x1 = x[1 * s + i];
    const f32x4 x2 = x[2 * s + i];
    const f32x4 x3 = x[3 * s + i];
    const f32x4 x4 = x[4 * s + i];
    const f32x4 x5 = x[5 * s + i];
    const f32x4 x6 = x[6 * s + i];
    const f32x4 x7 = x[7 * s + i];

    // Phase 2: serial v-chain (registers only) + non-temporal stores.
    f32x4 v = (f32x4)(0.0f);
    __builtin_nontemporal_store(step4(v, x0, th), &out[0 * s + i]);
    __builtin_nontemporal_store(step4(v, x1, th), &out[1 * s + i]);
    __builtin_nontemporal_store(step4(v, x2, th), &out[2 * s + i]);
    __builtin_nontemporal_store(step4(v, x3, th), &out[3 * s + i]);
    __builtin_nontemporal_store(step4(v, x4, th), &out[4 * s + i]);
    __builtin_nontemporal_store(step4(v, x5, th), &out[5 * s + i]);
    __builtin_nontemporal_store(step4(v, x6, th), &out[6 * s + i]);
    __builtin_nontemporal_store(step4(v, x7, th), &out[7 * s + i]);
}

extern "C" void kernel_launch(void* const* d_in, const int* in_sizes, int n_in,
                              void* d_out, int out_size, void* d_ws, size_t ws_size,
                              hipStream_t stream) {
    const float* x   = (const float*)d_in[0];
    const float* vth = (const float*)d_in[1];
    float*       out = (float*)d_out;

    // in_sizes[0] = T*B*N; per-timestep element count = total / T.
    const int total = in_sizes[0];
    const int bn    = total / kT;
    const int n4    = bn / 4;   // B*N = 4,194,304 -> n4 = 1,048,576

    const int block = 256;
    const int grid  = (n4 + block - 1) / block;   // 4096 blocks, 1 float4/thread
    lmht_pn_kernel<<<grid, block, 0, stream>>>(
        (const f32x4*)x, vth, (f32x4*)out, n4);
}

// Round 10
// 44.638 us; speedup vs baseline: 1.0496x; 1.0496x over previous
//
#include <hip/hip_runtime.h>

// LMHT neuron with multi-level positive/negative quantization.
// x: [T=8, B=64, N=65536] fp32; v_threshold: [1] fp32.
// Per neuron: v += x[t]; k = trunc(clamp(v/th,-4,4)); out[t]=k*th; v-=out[t].
// Memory-bound streaming scan. History:
//   R4 47.2us baseline (plain float4 stores)
//   R6 __builtin_nontemporal_store: neutral (FETCH pinned 65.5MB -> L3
//      write-allocation not steerable on gfx950)
//   R7 sc0sc1nt asm store + "memory" clobber: 44.58us  <- BEST, correct
//   R8 source-hoisted loads: undone by regalloc (VGPR stays 28), 46.9us
//   R9 clobberless asm + sched_barrier: WRONG RESULTS (absmax 4.0) -> the
//      "memory" clobber is required for correctness of inline-asm stores.
// This round: exact revert to R7. Ceiling model: 262 MB demand traffic /
// 6.29 TB/s copy ceiling = 41.7 us; R7 measured 44.58 us = 94%.

constexpr int   kT = 8;
constexpr float kL = 4.0f;

typedef float f32x4 __attribute__((ext_vector_type(4)));

__device__ __forceinline__ float quant_pn(float v, float th) {
    float k = v / th;                       // true IEEE div; matches jnp semantics
    k = fminf(fmaxf(k, -kL), kL);           // clamp to [-L, L]
    k = truncf(k);                          // floor-toward-zero == where(k>0,floor)+where(k<0,ceil)
    return k * th;
}

__device__ __forceinline__ void store_stream(f32x4* p, f32x4 v) {
    // System-scope non-temporal store. "memory" clobber is REQUIRED (R9
    // without it produced wrong results).
    asm volatile("global_store_dwordx4 %0, %1, off sc0 sc1 nt"
                 :: "v"(p), "v"(v) : "memory");
}

__global__ __launch_bounds__(256) void lmht_pn_kernel(
    const f32x4* __restrict__ x,
    const float* __restrict__ vth,
    f32x4* __restrict__ out,
    int n4)   // (B*N)/4 float4 elements per timestep
{
    const float th = vth[0];
    const int idx    = blockIdx.x * blockDim.x + threadIdx.x;
    const int stride = gridDim.x * blockDim.x;

    for (int i = idx; i < n4; i += stride) {
        f32x4 v = (f32x4)(0.0f);
        #pragma unroll
        for (int t = 0; t < kT; ++t) {
            f32x4 xt = x[(size_t)t * (size_t)n4 + (size_t)i];
            f32x4 o;
            v.x += xt.x;  o.x = quant_pn(v.x, th);  v.x -= o.x;
            v.y += xt.y;  o.y = quant_pn(v.y, th);  v.y -= o.y;
            v.z += xt.z;  o.z = quant_pn(v.z, th);  v.z -= o.z;
            v.w += xt.w;  o.w = quant_pn(v.w, th);  v.w -= o.w;
            store_stream(&out[(size_t)t * (size_t)n4 + (size_t)i], o);
        }
    }
}

extern "C" void kernel_launch(void* const* d_in, const int* in_sizes, int n_in,
                              void* d_out, int out_size, void* d_ws, size_t ws_size,
                              hipStream_t stream) {
    const float* x   = (const float*)d_in[0];
    const float* vth = (const float*)d_in[1];
    float*       out = (float*)d_out;

    // in_sizes[0] = T*B*N; per-timestep element count = total / T.
    const int total = in_sizes[0];
    const int bn    = total / kT;
    const int n4    = bn / 4;   // B*N = 4,194,304 -> n4 = 1,048,576

    const int block = 256;
    int grid = (n4 + block - 1) / block;    // 4096 blocks: 1 float4/thread
    lmht_pn_kernel<<<grid, block, 0, stream>>>(
        (const f32x4*)x, vth, (f32x4*)out, n4);
}